// Round 10
// baseline (265.519 us; speedup 1.0000x reference)
//
#include <hip/hip_runtime.h>
#include <hip/hip_bf16.h>
#include <math.h>

typedef __bf16 bf16_t;
typedef __bf16 bf16x4_t __attribute__((ext_vector_type(4)));
typedef __bf16 bf16x8_t __attribute__((ext_vector_type(8)));
typedef float  f32x4_t  __attribute__((ext_vector_type(4)));

#define SEQ 2048
#define DM  1024
#define NH  16
#define DK  64
// log2(10000)/32
#define ROPE_C 0.4152410118609203f
// log2(e)/sqrt(dk)
#define EXP_C (1.4426950408889634f / 8.0f)

// ---------------- fused fp32 -> bf16 cast: x, wq, wk, wv, wo ----------------
__global__ __launch_bounds__(256)
void cast_all(const float* __restrict__ x,  const float* __restrict__ wq,
              const float* __restrict__ wk, const float* __restrict__ wv,
              const float* __restrict__ wo, bf16_t* __restrict__ dst) {
  int i = blockIdx.x * 256 + threadIdx.x;   // float4 index, 0..2097151
  const float* s;
  if (i < 1048576) {
    s = x + (size_t)i * 4;
  } else {
    int j = i - 1048576;
    int w = j >> 18;                        // 262144 float4 per weight
    const float* base = (w == 0) ? wq : (w == 1) ? wk : (w == 2) ? wv : wo;
    s = base + (size_t)(j & 262143) * 4;
  }
  float4 v = *(const float4*)s;
  bf16x4_t o;
  o.x = (bf16_t)v.x; o.y = (bf16_t)v.y; o.z = (bf16_t)v.z; o.w = (bf16_t)v.w;
  ((bf16x4_t*)dst)[i] = o;
}

// ---------------- RoPE sin/cos LUT: lut[s*32+f] = (sin, cos)(s * base^(-f/32)) ----
__global__ __launch_bounds__(256)
void rope_lut_kernel(float2* __restrict__ lut) {
  int i = blockIdx.x * 256 + threadIdx.x;   // 0..65535
  int s = i >> 5, f = i & 31;
  float ang = (float)s * exp2f(-ROPE_C * (float)f);
  float sn, cs;
  sincosf(ang, &sn, &cs);
  lut[i] = make_float2(sn, cs);
}

// ---------------- Q/K GEMM with fused RoPE ----------------
// Grid (16, 32): bn 0..7 -> Q, bn 8..15 -> K. 128x128 tiles.
// NOTE: single epilogue path, no libm calls (multi-path epilogue + inline
// sincosf caused 64-VGPR alloc + acc spill, R4-R6). Plain launch_bounds only.
__global__ __launch_bounds__(256)
void gemm_qk(const bf16_t* __restrict__ A, const bf16_t* __restrict__ Wq,
             const bf16_t* __restrict__ Wk, const float* __restrict__ bq,
             const float* __restrict__ bk, const float2* __restrict__ lut,
             bf16_t* __restrict__ Qb, bf16_t* __restrict__ Kb) {
  const int K = 1024;
  __shared__ bf16_t As[128 * 40];
  __shared__ bf16_t Bs[128 * 40];

  const int tid  = threadIdx.x;
  const int w    = tid >> 6;
  const int lane = tid & 63;
  const int quad = lane >> 4;
  const int lrow = lane & 15;
  const int wm = (w >> 1) * 64, wn = (w & 1) * 64;
  const int bm = blockIdx.y, bn = blockIdx.x;

  const int isK = bn >> 3;                  // 0 = Q, 1 = K (block-uniform)
  const int bnl = bn & 7;
  const bf16_t* Ablk = A + (size_t)(bm * 128) * K;
  const bf16_t* Bblk = (isK ? Wk : Wq) + (size_t)(bnl * 128) * K;
  const float*  bias = isK ? bk : bq;
  bf16_t* D = isK ? Kb : Qb;

  f32x4_t acc[4][4] = {};

  const int lr = tid >> 1;
  const int lc = (tid & 1) * 16;

  for (int k0 = 0; k0 < K; k0 += 32) {
    *(uint4*)(&As[lr * 40 + lc])     = *(const uint4*)(&Ablk[(size_t)lr * K + k0 + lc]);
    *(uint4*)(&As[lr * 40 + lc + 8]) = *(const uint4*)(&Ablk[(size_t)lr * K + k0 + lc + 8]);
    *(uint4*)(&Bs[lr * 40 + lc])     = *(const uint4*)(&Bblk[(size_t)lr * K + k0 + lc]);
    *(uint4*)(&Bs[lr * 40 + lc + 8]) = *(const uint4*)(&Bblk[(size_t)lr * K + k0 + lc + 8]);
    __syncthreads();

    bf16x8_t af[4], bf[4];
#pragma unroll
    for (int mi = 0; mi < 4; mi++)
      af[mi] = *(const bf16x8_t*)(&As[(wm + mi * 16 + lrow) * 40 + quad * 8]);
#pragma unroll
    for (int ni = 0; ni < 4; ni++)
      bf[ni] = *(const bf16x8_t*)(&Bs[(wn + ni * 16 + lrow) * 40 + quad * 8]);
#pragma unroll
    for (int mi = 0; mi < 4; mi++)
#pragma unroll
      for (int ni = 0; ni < 4; ni++)
        acc[mi][ni] = __builtin_amdgcn_mfma_f32_16x16x32_bf16(af[mi], bf[ni], acc[mi][ni], 0, 0, 0);
    __syncthreads();
  }

  const int brow = bm * 128 + wm;
  const int cbase = bnl * 128 + wn;

#pragma unroll
  for (int ni = 0; ni < 4; ni++) {
    const int col = cbase + ni * 16 + lrow;  // 0..1023
    const float bv = bias[col];
    const int t = col & 63;
    const int h = col >> 6;
    const int fidx = t >> 1;
#pragma unroll
    for (int mi = 0; mi < 4; mi++) {
      f32x4_t v = acc[mi][ni];
#pragma unroll
      for (int r = 0; r < 4; r++) {
        const int row = brow + mi * 16 + quad * 4 + r;  // token
        const int s = row & (SEQ - 1);
        float val = v[r] + bv;
        const float2 sc = lut[s * 32 + fidx];
        const float pv = __shfl_xor(val, 1);            // partner column col^1
        val = (t & 1) ? (val * sc.y + pv * sc.x) : (val * sc.y - pv * sc.x);
        const int b = row >> 11;
        const size_t o = (((size_t)(b * NH + h) * SEQ) + s) * DK + t;
        D[o] = (bf16_t)val;
      }
    }
  }
}

// ---------------- V^T GEMM: Vt = (x Wv^T + bv)^T in (B,H,dk,S) ----------------
// A = Wv (rows=features), B = x (rows=tokens). 64(f)x128(t) tiles -> grid
// (32, 16) = 512 blocks = 2/CU.
__global__ __launch_bounds__(256)
void gemm_vt(const bf16_t* __restrict__ A, const bf16_t* __restrict__ Bx,
             const float* __restrict__ bias, bf16_t* __restrict__ Vtb) {
  const int K = 1024;
  __shared__ bf16_t As[64 * 40];
  __shared__ bf16_t Bs[128 * 40];

  const int tid  = threadIdx.x;
  const int w    = tid >> 6;
  const int lane = tid & 63;
  const int quad = lane >> 4;
  const int lrow = lane & 15;
  const int wm = (w >> 1) * 32, wn = (w & 1) * 64;
  const int bm = blockIdx.y, bn = blockIdx.x;

  const bf16_t* Ablk = A  + (size_t)(bm * 64) * K;    // features
  const bf16_t* Bblk = Bx + (size_t)(bn * 128) * K;   // tokens

  f32x4_t acc[2][4] = {};

  const int lrA = tid >> 2;
  const int lcA = (tid & 3) * 8;
  const int lrB = tid >> 1;
  const int lcB = (tid & 1) * 16;

  for (int k0 = 0; k0 < K; k0 += 32) {
    *(uint4*)(&As[lrA * 40 + lcA])    = *(const uint4*)(&Ablk[(size_t)lrA * K + k0 + lcA]);
    *(uint4*)(&Bs[lrB * 40 + lcB])    = *(const uint4*)(&Bblk[(size_t)lrB * K + k0 + lcB]);
    *(uint4*)(&Bs[lrB * 40 + lcB + 8])= *(const uint4*)(&Bblk[(size_t)lrB * K + k0 + lcB + 8]);
    __syncthreads();

    bf16x8_t af[2], bf[4];
#pragma unroll
    for (int mi = 0; mi < 2; mi++)
      af[mi] = *(const bf16x8_t*)(&As[(wm + mi * 16 + lrow) * 40 + quad * 8]);
#pragma unroll
    for (int ni = 0; ni < 4; ni++)
      bf[ni] = *(const bf16x8_t*)(&Bs[(wn + ni * 16 + lrow) * 40 + quad * 8]);
#pragma unroll
    for (int mi = 0; mi < 2; mi++)
#pragma unroll
      for (int ni = 0; ni < 4; ni++)
        acc[mi][ni] = __builtin_amdgcn_mfma_f32_16x16x32_bf16(af[mi], bf[ni], acc[mi][ni], 0, 0, 0);
    __syncthreads();
  }

  const int fbase = bm * 64 + wm;
  const int tbase = bn * 128 + wn;

#pragma unroll
  for (int ni = 0; ni < 4; ni++) {
    const int t = tbase + ni * 16 + lrow;    // token 0..4095
    const int b = t >> 11;
    const int s = t & (SEQ - 1);
#pragma unroll
    for (int mi = 0; mi < 2; mi++) {
      f32x4_t v = acc[mi][ni];
      const int f = fbase + mi * 16 + quad * 4;  // feature base (mult of 4)
      const int h = f >> 6, d = f & 63;
#pragma unroll
      for (int r = 0; r < 4; r++)
        Vtb[((size_t)((b * NH + h) * DK + d + r)) * SEQ + s] = (bf16_t)(v[r] + bias[f + r]);
    }
  }
}

// ---------------- output GEMM: out[M,N] = AO[M,K] * Wo[N,K]^T + bo ----------------
__global__ __launch_bounds__(256)
void gemm_out(const bf16_t* __restrict__ A, const bf16_t* __restrict__ Bw,
              const float* __restrict__ bias, float* __restrict__ D) {
  const int K = 1024;
  __shared__ bf16_t As[128 * 40];
  __shared__ bf16_t Bs[64 * 40];

  const int tid  = threadIdx.x;
  const int w    = tid >> 6;
  const int lane = tid & 63;
  const int quad = lane >> 4;
  const int lrow = lane & 15;
  const int wm = (w >> 1) * 64, wn = (w & 1) * 32;
  const int bm = blockIdx.y, bn = blockIdx.x;

  const bf16_t* Ablk = A  + (size_t)(bm * 128) * K;
  const bf16_t* Bblk = Bw + (size_t)(bn * 64) * K;

  f32x4_t acc[4][2] = {};

  const int lr = tid >> 1;
  const int lc = (tid & 1) * 16;
  const int lrB = tid >> 2;
  const int lcB = (tid & 3) * 8;

  for (int k0 = 0; k0 < K; k0 += 32) {
    *(uint4*)(&As[lr * 40 + lc])     = *(const uint4*)(&Ablk[(size_t)lr * K + k0 + lc]);
    *(uint4*)(&As[lr * 40 + lc + 8]) = *(const uint4*)(&Ablk[(size_t)lr * K + k0 + lc + 8]);
    *(uint4*)(&Bs[lrB * 40 + lcB])   = *(const uint4*)(&Bblk[(size_t)lrB * K + k0 + lcB]);
    __syncthreads();

    bf16x8_t af[4], bf[2];
#pragma unroll
    for (int mi = 0; mi < 4; mi++)
      af[mi] = *(const bf16x8_t*)(&As[(wm + mi * 16 + lrow) * 40 + quad * 8]);
#pragma unroll
    for (int ni = 0; ni < 2; ni++)
      bf[ni] = *(const bf16x8_t*)(&Bs[(wn + ni * 16 + lrow) * 40 + quad * 8]);
#pragma unroll
    for (int mi = 0; mi < 4; mi++)
#pragma unroll
      for (int ni = 0; ni < 2; ni++)
        acc[mi][ni] = __builtin_amdgcn_mfma_f32_16x16x32_bf16(af[mi], bf[ni], acc[mi][ni], 0, 0, 0);
    __syncthreads();
  }

#pragma unroll
  for (int ni = 0; ni < 2; ni++) {
    const int col = bn * 64 + wn + ni * 16 + lrow;
    const float bvv = bias[col];
#pragma unroll
    for (int mi = 0; mi < 4; mi++) {
      f32x4_t v = acc[mi][ni];
#pragma unroll
      for (int r = 0; r < 4; r++) {
        const int row = bm * 128 + wm + mi * 16 + quad * 4 + r;
        D[(size_t)row * DM + col] = v[r] + bvv;
      }
    }
  }
}

// ---------------- flash attention v5: wave split-K + perm-packed P ----------------
// Block = 64 q-rows, 4 waves: wave (qsub=w>>1, ksub=w&1) computes 32 q x the
// ksub-half (64 keys) of each 128-key tile. Partial (accO, lsum) are linearly
// combinable (no-max softmax) -> one LDS exchange at the end. Grid (32,32) =
// 1024 blocks = 4 blocks/CU (LDS 35840 x 4 = 143 KB) -> 2x occupancy vs R8.
// P pack: v_perm_b32 truncates 2 f32 -> bf16x2 in 1 instr (bias ~2^-9,
// cancels in P*V/sum(p)).
__global__ __launch_bounds__(256)
void attn_kernel(const bf16_t* __restrict__ Q, const bf16_t* __restrict__ K,
                 const bf16_t* __restrict__ Vt, bf16_t* __restrict__ AO) {
  __shared__ __align__(16) bf16_t Ks[128 * 72];   // [key][dk]; reused as f32 exchange
  __shared__ __align__(16) bf16_t Vs[64 * 136];   // [dk][key]; tail reused for lsum

  const int tid  = threadIdx.x;
  const int w    = tid >> 6;
  const int lane = tid & 63;
  const int quad = lane >> 4;
  const int lrow = lane & 15;
  const int bh   = blockIdx.y;
  const int qsub = w >> 1;
  const int ksub = w & 1;
  const int q0 = blockIdx.x * 64 + qsub * 32;

  const bf16_t* Qh  = Q  + (size_t)bh * SEQ * DK;
  const bf16_t* Kh  = K  + (size_t)bh * SEQ * DK;
  const bf16_t* Vth = Vt + (size_t)bh * DK * SEQ;

  // Q fragments, pre-scaled by EXP_C (B-operand of S^T mfma)
  bf16x8_t qf[2][2];
#pragma unroll
  for (int mi = 0; mi < 2; mi++)
#pragma unroll
    for (int c = 0; c < 2; c++) {
      bf16x8_t t = *(const bf16x8_t*)(&Qh[(size_t)(q0 + mi * 16 + lrow) * DK + c * 32 + quad * 8]);
#pragma unroll
      for (int i = 0; i < 8; i++) t[i] = (bf16_t)((float)t[i] * EXP_C);
      qf[mi][c] = t;
    }

  f32x4_t accO[2][4] = {};
  float lsum[2] = {0.f, 0.f};

  const int krow = tid >> 1;            // 0..127 (K staging)
  const int kcol = (tid & 1) * 32;
  const int vrow = tid >> 2;            // 0..63 (V staging)
  const int vcol = (tid & 3) * 32;

  for (int kt = 0; kt < SEQ / 128; ++kt) {
    const int kb = kt * 128;
#pragma unroll
    for (int u = 0; u < 4; u++)
      *(uint4*)(&Ks[krow * 72 + kcol + u * 8]) = *(const uint4*)(&Kh[(size_t)(kb + krow) * DK + kcol + u * 8]);
#pragma unroll
    for (int u = 0; u < 4; u++)
      *(uint4*)(&Vs[vrow * 136 + vcol + u * 8]) = *(const uint4*)(&Vth[(size_t)vrow * SEQ + kb + vcol + u * 8]);
    __syncthreads();

#pragma unroll
    for (int c2 = 0; c2 < 2; ++c2) {        // this wave's two 32-key chunks
      const int c2g = ksub * 2 + c2;
      uint2 pk[2][2];                       // [kk2][mi]
#pragma unroll
      for (int kk2 = 0; kk2 < 2; ++kk2) {
        const int kk = c2g * 2 + kk2;       // 16-key tile
        bf16x8_t kf0 = *(const bf16x8_t*)(&Ks[(kk * 16 + lrow) * 72 + quad * 8]);
        bf16x8_t kf1 = *(const bf16x8_t*)(&Ks[(kk * 16 + lrow) * 72 + 32 + quad * 8]);
#pragma unroll
        for (int mi = 0; mi < 2; ++mi) {
          f32x4_t z = {};
          z = __builtin_amdgcn_mfma_f32_16x16x32_bf16(kf0, qf[mi][0], z, 0, 0, 0);
          z = __builtin_amdgcn_mfma_f32_16x16x32_bf16(kf1, qf[mi][1], z, 0, 0, 0);
          const float p0 = exp2f(z[0]), p1 = exp2f(z[1]);
          const float p2 = exp2f(z[2]), p3 = exp2f(z[3]);
          lsum[mi] += (p0 + p1) + (p2 + p3);
          pk[kk2][mi].x = __builtin_amdgcn_perm(__builtin_bit_cast(unsigned, p1),
                                                __builtin_bit_cast(unsigned, p0), 0x07060302u);
          pk[kk2][mi].y = __builtin_amdgcn_perm(__builtin_bit_cast(unsigned, p3),
                                                __builtin_bit_cast(unsigned, p2), 0x07060302u);
        }
      }
      bf16x8_t pf[2];
#pragma unroll
      for (int mi = 0; mi < 2; ++mi) {
        uint4 pfu;
        pfu.x = pk[0][mi].x; pfu.y = pk[0][mi].y;
        pfu.z = pk[1][mi].x; pfu.w = pk[1][mi].y;
        pf[mi] = __builtin_bit_cast(bf16x8_t, pfu);
      }
#pragma unroll
      for (int nt = 0; nt < 4; ++nt) {
        const bf16_t* vbase = &Vs[(nt * 16 + lrow) * 136 + c2g * 32 + quad * 4];
        bf16x8_t vf;
        *(bf16x4_t*)(&vf)       = *(const bf16x4_t*)(vbase);
        *((bf16x4_t*)(&vf) + 1) = *(const bf16x4_t*)(vbase + 16);
        accO[0][nt] = __builtin_amdgcn_mfma_f32_16x16x32_bf16(pf[0], vf, accO[0][nt], 0, 0, 0);
        accO[1][nt] = __builtin_amdgcn_mfma_f32_16x16x32_bf16(pf[1], vf, accO[1][nt], 0, 0, 0);
      }
    }
    __syncthreads();
  }

  // ---- cross-ksub combine (reuse Ks as f32 scratch; stride 36 dw: conflict-free b128)
  float* Xa = (float*)Ks;
  float* Xl = (float*)Vs;
  if (ksub == 1) {
    const int base = (qsub * 64 + lane) * 36;
#pragma unroll
    for (int mi = 0; mi < 2; mi++)
#pragma unroll
      for (int nt = 0; nt < 4; nt++)
        *(f32x4_t*)(&Xa[base + (mi * 4 + nt) * 4]) = accO[mi][nt];
#pragma unroll
    for (int mi = 0; mi < 2; mi++)
      Xl[(qsub * 2 + mi) * 64 + lane] = lsum[mi];
  }
  __syncthreads();
  if (ksub == 0) {
    const int base = (qsub * 64 + lane) * 36;
#pragma unroll
    for (int mi = 0; mi < 2; mi++)
#pragma unroll
      for (int nt = 0; nt < 4; nt++)
        accO[mi][nt] += *(const f32x4_t*)(&Xa[base + (mi * 4 + nt) * 4]);
#pragma unroll
    for (int mi = 0; mi < 2; mi++) {
      lsum[mi] += Xl[(qsub * 2 + mi) * 64 + lane];
      lsum[mi] += __shfl_xor(lsum[mi], 16);
      lsum[mi] += __shfl_xor(lsum[mi], 32);
    }
    float linv[2][4];
#pragma unroll
    for (int mi = 0; mi < 2; mi++)
#pragma unroll
      for (int r = 0; r < 4; r++)
        linv[mi][r] = 1.0f / __shfl(lsum[mi], quad * 4 + r);

    const int b = bh >> 4, h = bh & 15;
#pragma unroll
    for (int mi = 0; mi < 2; mi++)
#pragma unroll
      for (int nt = 0; nt < 4; nt++)
#pragma unroll
        for (int r = 0; r < 4; r++) {
          const int srowq = q0 + mi * 16 + quad * 4 + r;
          const float val = accO[mi][nt][r] * linv[mi][r];
          const size_t o = ((size_t)(b * SEQ + srowq)) * DM + h * DK + nt * 16 + lrow;
          AO[o] = (bf16_t)val;
        }
  }
}

extern "C" void kernel_launch(void* const* d_in, const int* in_sizes, int n_in,
                              void* d_out, int out_size, void* d_ws, size_t ws_size,
                              hipStream_t stream) {
  const float* x  = (const float*)d_in[0];
  const float* wq = (const float*)d_in[1];
  const float* bq = (const float*)d_in[2];
  const float* wk = (const float*)d_in[3];
  const float* bk = (const float*)d_in[4];
  const float* wv = (const float*)d_in[5];
  const float* bv = (const float*)d_in[6];
  const float* wo = (const float*)d_in[7];
  const float* bo = (const float*)d_in[8];
  float* out = (float*)d_out;

  char* ws = (char*)d_ws;
  bf16_t* xb   = (bf16_t*)(ws);             // 8 MB
  bf16_t* wqb  = (bf16_t*)(ws + 8388608);   // 2 MB
  bf16_t* wkb  = (bf16_t*)(ws + 10485760);  // 2 MB
  bf16_t* wvb  = (bf16_t*)(ws + 12582912);  // 2 MB
  bf16_t* wob  = (bf16_t*)(ws + 14680064);  // 2 MB
  bf16_t* Qb   = (bf16_t*)(ws + 16777216);  // 8 MB (B,H,S,dk)
  bf16_t* Kb   = (bf16_t*)(ws + 25165824);  // 8 MB (B,H,S,dk)
  bf16_t* Vtb  = (bf16_t*)(ws + 33554432);  // 8 MB (B,H,dk,S)
  bf16_t* AOb  = (bf16_t*)(ws + 41943040);  // 8 MB (B,S,D)
  float2* lut  = (float2*)(ws + 50331648);  // 512 KB RoPE LUT

  cast_all<<<8192, 256, 0, stream>>>(x, wq, wk, wv, wo, xb);
  rope_lut_kernel<<<256, 256, 0, stream>>>(lut);

  gemm_qk<<<dim3(16, 32), 256, 0, stream>>>(xb, wqb, wkb, bq, bk, lut, Qb, Kb);
  gemm_vt<<<dim3(32, 16), 256, 0, stream>>>(wvb, xb, bv, Vtb);

  attn_kernel<<<dim3(SEQ / 64, 2 * NH), 256, 0, stream>>>(Qb, Kb, Vtb, AOb);

  gemm_out<<<dim3(16, 32), 256, 0, stream>>>(AOb, wob, bo, out);
}

// Round 11
// 239.935 us; speedup vs baseline: 1.1066x; 1.1066x over previous
//
#include <hip/hip_runtime.h>
#include <hip/hip_bf16.h>
#include <math.h>

typedef __bf16 bf16_t;
typedef __bf16 bf16x4_t __attribute__((ext_vector_type(4)));
typedef __bf16 bf16x8_t __attribute__((ext_vector_type(8)));
typedef float  f32x4_t  __attribute__((ext_vector_type(4)));

#define SEQ 2048
#define DM  1024
#define NH  16
#define DK  64
// log2(10000)/32
#define ROPE_C 0.4152410118609203f
// log2(e)/sqrt(dk)
#define EXP_C (1.4426950408889634f / 8.0f)

// ---------------- fused fp32 -> bf16 cast: x, wq, wk, wv, wo ----------------
__global__ __launch_bounds__(256)
void cast_all(const float* __restrict__ x,  const float* __restrict__ wq,
              const float* __restrict__ wk, const float* __restrict__ wv,
              const float* __restrict__ wo, bf16_t* __restrict__ dst) {
  int i = blockIdx.x * 256 + threadIdx.x;   // float4 index, 0..2097151
  const float* s;
  if (i < 1048576) {
    s = x + (size_t)i * 4;
  } else {
    int j = i - 1048576;
    int w = j >> 18;                        // 262144 float4 per weight
    const float* base = (w == 0) ? wq : (w == 1) ? wk : (w == 2) ? wv : wo;
    s = base + (size_t)(j & 262143) * 4;
  }
  float4 v = *(const float4*)s;
  bf16x4_t o;
  o.x = (bf16_t)v.x; o.y = (bf16_t)v.y; o.z = (bf16_t)v.z; o.w = (bf16_t)v.w;
  ((bf16x4_t*)dst)[i] = o;
}

// ---------------- RoPE sin/cos LUT: lut[s*32+f] = (sin, cos)(s * base^(-f/32)) ----
__global__ __launch_bounds__(256)
void rope_lut_kernel(float2* __restrict__ lut) {
  int i = blockIdx.x * 256 + threadIdx.x;   // 0..65535
  int s = i >> 5, f = i & 31;
  float ang = (float)s * exp2f(-ROPE_C * (float)f);
  float sn, cs;
  sincosf(ang, &sn, &cs);
  lut[i] = make_float2(sn, cs);
}

// ---------------- Q/K GEMM with fused RoPE (512 thr, 8 waves) ----------------
// Grid (16, 32): bn 0..7 -> Q, bn 8..15 -> K. 128x128 block tile; wave tile
// 32(M)x64(N). 512 threads doubles waves/CU (8->16) at unchanged per-block
// staging (R10 lesson: never duplicate staging to buy occupancy).
// NOTE: single epilogue path, no libm (R4-R6 spill). Plain launch_bounds.
__global__ __launch_bounds__(512)
void gemm_qk(const bf16_t* __restrict__ A, const bf16_t* __restrict__ Wq,
             const bf16_t* __restrict__ Wk, const float* __restrict__ bq,
             const float* __restrict__ bk, const float2* __restrict__ lut,
             bf16_t* __restrict__ Qb, bf16_t* __restrict__ Kb) {
  const int K = 1024;
  __shared__ bf16_t As[128 * 40];
  __shared__ bf16_t Bs[128 * 40];

  const int tid  = threadIdx.x;
  const int w    = tid >> 6;                // 0..7
  const int lane = tid & 63;
  const int quad = lane >> 4;
  const int lrow = lane & 15;
  const int wm = (w >> 1) * 32, wn = (w & 1) * 64;
  const int bm = blockIdx.y, bn = blockIdx.x;

  const int isK = bn >> 3;                  // 0 = Q, 1 = K (block-uniform)
  const int bnl = bn & 7;
  const bf16_t* Ablk = A + (size_t)(bm * 128) * K;
  const bf16_t* Bblk = (isK ? Wk : Wq) + (size_t)(bnl * 128) * K;
  const float*  bias = isK ? bk : bq;
  bf16_t* D = isK ? Kb : Qb;

  f32x4_t acc[2][4] = {};

  const int lr = tid >> 2;                  // 0..127
  const int lc = (tid & 3) * 8;             // 0,8,16,24

  for (int k0 = 0; k0 < K; k0 += 32) {
    *(uint4*)(&As[lr * 40 + lc]) = *(const uint4*)(&Ablk[(size_t)lr * K + k0 + lc]);
    *(uint4*)(&Bs[lr * 40 + lc]) = *(const uint4*)(&Bblk[(size_t)lr * K + k0 + lc]);
    __syncthreads();

    bf16x8_t af[2], bf[4];
#pragma unroll
    for (int mi = 0; mi < 2; mi++)
      af[mi] = *(const bf16x8_t*)(&As[(wm + mi * 16 + lrow) * 40 + quad * 8]);
#pragma unroll
    for (int ni = 0; ni < 4; ni++)
      bf[ni] = *(const bf16x8_t*)(&Bs[(wn + ni * 16 + lrow) * 40 + quad * 8]);
#pragma unroll
    for (int mi = 0; mi < 2; mi++)
#pragma unroll
      for (int ni = 0; ni < 4; ni++)
        acc[mi][ni] = __builtin_amdgcn_mfma_f32_16x16x32_bf16(af[mi], bf[ni], acc[mi][ni], 0, 0, 0);
    __syncthreads();
  }

  const int brow = bm * 128 + wm;
  const int cbase = bnl * 128 + wn;

#pragma unroll
  for (int ni = 0; ni < 4; ni++) {
    const int col = cbase + ni * 16 + lrow;  // 0..1023
    const float bv = bias[col];
    const int t = col & 63;
    const int h = col >> 6;
    const int fidx = t >> 1;
#pragma unroll
    for (int mi = 0; mi < 2; mi++) {
      f32x4_t v = acc[mi][ni];
#pragma unroll
      for (int r = 0; r < 4; r++) {
        const int row = brow + mi * 16 + quad * 4 + r;  // token
        const int s = row & (SEQ - 1);
        float val = v[r] + bv;
        const float2 sc = lut[s * 32 + fidx];
        const float pv = __shfl_xor(val, 1);            // partner column col^1
        val = (t & 1) ? (val * sc.y + pv * sc.x) : (val * sc.y - pv * sc.x);
        const int b = row >> 11;
        const size_t o = (((size_t)(b * NH + h) * SEQ) + s) * DK + t;
        D[o] = (bf16_t)val;
      }
    }
  }
}

// ---------------- V^T GEMM: Vt = (x Wv^T + bv)^T in (B,H,dk,S), 512 thr --------
// 64(f)x128(t) block tile, wave tile 32x32. Grid (32, 16) = 512 blocks.
__global__ __launch_bounds__(512)
void gemm_vt(const bf16_t* __restrict__ A, const bf16_t* __restrict__ Bx,
             const float* __restrict__ bias, bf16_t* __restrict__ Vtb) {
  const int K = 1024;
  __shared__ bf16_t As[64 * 40];
  __shared__ bf16_t Bs[128 * 40];

  const int tid  = threadIdx.x;
  const int w    = tid >> 6;                // 0..7
  const int lane = tid & 63;
  const int quad = lane >> 4;
  const int lrow = lane & 15;
  const int wm = (w >> 2) * 32, wn = (w & 3) * 32;
  const int bm = blockIdx.y, bn = blockIdx.x;

  const bf16_t* Ablk = A  + (size_t)(bm * 64) * K;    // features
  const bf16_t* Bblk = Bx + (size_t)(bn * 128) * K;   // tokens

  f32x4_t acc[2][2] = {};

  const int lrA = tid >> 3;                 // 0..63
  const int lcA = (tid & 7) * 4;            // 0..28
  const int lrB = tid >> 2;                 // 0..127
  const int lcB = (tid & 3) * 8;            // 0..24

  for (int k0 = 0; k0 < K; k0 += 32) {
    *(uint2*)(&As[lrA * 40 + lcA]) = *(const uint2*)(&Ablk[(size_t)lrA * K + k0 + lcA]);
    *(uint4*)(&Bs[lrB * 40 + lcB]) = *(const uint4*)(&Bblk[(size_t)lrB * K + k0 + lcB]);
    __syncthreads();

    bf16x8_t af[2], bf[2];
#pragma unroll
    for (int mi = 0; mi < 2; mi++)
      af[mi] = *(const bf16x8_t*)(&As[(wm + mi * 16 + lrow) * 40 + quad * 8]);
#pragma unroll
    for (int ni = 0; ni < 2; ni++)
      bf[ni] = *(const bf16x8_t*)(&Bs[(wn + ni * 16 + lrow) * 40 + quad * 8]);
#pragma unroll
    for (int mi = 0; mi < 2; mi++)
#pragma unroll
      for (int ni = 0; ni < 2; ni++)
        acc[mi][ni] = __builtin_amdgcn_mfma_f32_16x16x32_bf16(af[mi], bf[ni], acc[mi][ni], 0, 0, 0);
    __syncthreads();
  }

  const int fbase = bm * 64 + wm;
  const int tbase = bn * 128 + wn;

#pragma unroll
  for (int ni = 0; ni < 2; ni++) {
    const int t = tbase + ni * 16 + lrow;    // token
    const int b = t >> 11;
    const int s = t & (SEQ - 1);
#pragma unroll
    for (int mi = 0; mi < 2; mi++) {
      f32x4_t v = acc[mi][ni];
      const int f = fbase + mi * 16 + quad * 4;  // feature base (mult of 4)
      const int h = f >> 6, d = f & 63;
#pragma unroll
      for (int r = 0; r < 4; r++)
        Vtb[((size_t)((b * NH + h) * DK + d + r)) * SEQ + s] = (bf16_t)(v[r] + bias[f + r]);
    }
  }
}

// ---------------- output GEMM: out = AO * Wo^T + bo, 512 thr ----------------
// 128(M)x64(N) block tile, wave tile 32x32. Grid (16, 32) = 512 blocks.
__global__ __launch_bounds__(512)
void gemm_out(const bf16_t* __restrict__ A, const bf16_t* __restrict__ Bw,
              const float* __restrict__ bias, float* __restrict__ D) {
  const int K = 1024;
  __shared__ bf16_t As[128 * 40];
  __shared__ bf16_t Bs[64 * 40];

  const int tid  = threadIdx.x;
  const int w    = tid >> 6;                // 0..7
  const int lane = tid & 63;
  const int quad = lane >> 4;
  const int lrow = lane & 15;
  const int wm = (w >> 1) * 32, wn = (w & 1) * 32;
  const int bm = blockIdx.y, bn = blockIdx.x;

  const bf16_t* Ablk = A  + (size_t)(bm * 128) * K;
  const bf16_t* Bblk = Bw + (size_t)(bn * 64) * K;

  f32x4_t acc[2][2] = {};

  const int lr = tid >> 2;                  // 0..127
  const int lc = (tid & 3) * 8;
  const int lrB = tid >> 3;                 // 0..63
  const int lcB = (tid & 7) * 4;

  for (int k0 = 0; k0 < K; k0 += 32) {
    *(uint4*)(&As[lr * 40 + lc])   = *(const uint4*)(&Ablk[(size_t)lr * K + k0 + lc]);
    *(uint2*)(&Bs[lrB * 40 + lcB]) = *(const uint2*)(&Bblk[(size_t)lrB * K + k0 + lcB]);
    __syncthreads();

    bf16x8_t af[2], bf[2];
#pragma unroll
    for (int mi = 0; mi < 2; mi++)
      af[mi] = *(const bf16x8_t*)(&As[(wm + mi * 16 + lrow) * 40 + quad * 8]);
#pragma unroll
    for (int ni = 0; ni < 2; ni++)
      bf[ni] = *(const bf16x8_t*)(&Bs[(wn + ni * 16 + lrow) * 40 + quad * 8]);
#pragma unroll
    for (int mi = 0; mi < 2; mi++)
#pragma unroll
      for (int ni = 0; ni < 2; ni++)
        acc[mi][ni] = __builtin_amdgcn_mfma_f32_16x16x32_bf16(af[mi], bf[ni], acc[mi][ni], 0, 0, 0);
    __syncthreads();
  }

#pragma unroll
  for (int ni = 0; ni < 2; ni++) {
    const int col = bn * 64 + wn + ni * 16 + lrow;
    const float bvv = bias[col];
#pragma unroll
    for (int mi = 0; mi < 2; mi++) {
      f32x4_t v = acc[mi][ni];
#pragma unroll
      for (int r = 0; r < 4; r++) {
        const int row = bm * 128 + wm + mi * 16 + quad * 4 + r;
        D[(size_t)row * DM + col] = v[r] + bvv;
      }
    }
  }
}

// ---------------- flash attention v6: R8 structure @ 512 threads ----------------
// Block = 128 q-rows, 8 waves x 16 q-rows. K-tile 128. S^T + permuted-key PV
// (R8-verified). Same per-block staging as R8, 2x waves/CU (16 = 50% nominal).
__global__ __launch_bounds__(512)
void attn_kernel(const bf16_t* __restrict__ Q, const bf16_t* __restrict__ K,
                 const bf16_t* __restrict__ Vt, bf16_t* __restrict__ AO) {
  __shared__ bf16_t Ks[128 * 72];        // [key][dk]
  __shared__ bf16_t Vs[64 * 136];        // [dk][key]

  const int tid  = threadIdx.x;
  const int w    = tid >> 6;             // 0..7
  const int lane = tid & 63;
  const int quad = lane >> 4;
  const int lrow = lane & 15;
  const int bh = blockIdx.y;
  const int q0 = blockIdx.x * 128 + w * 16;

  const bf16_t* Qh  = Q  + (size_t)bh * SEQ * DK;
  const bf16_t* Kh  = K  + (size_t)bh * SEQ * DK;
  const bf16_t* Vth = Vt + (size_t)bh * DK * SEQ;

  // Q fragments for 16 q-rows, pre-scaled by EXP_C (B-operand of S^T mfma)
  bf16x8_t qf[2];
#pragma unroll
  for (int c = 0; c < 2; c++) {
    bf16x8_t t = *(const bf16x8_t*)(&Qh[(size_t)(q0 + lrow) * DK + c * 32 + quad * 8]);
#pragma unroll
    for (int i = 0; i < 8; i++) t[i] = (bf16_t)((float)t[i] * EXP_C);
    qf[c] = t;
  }

  f32x4_t accO[4] = {};
  float lsum = 0.f;

  const int krow = tid >> 2;            // 0..127 (K staging)
  const int kcol = (tid & 3) * 16;
  const int vrow = tid >> 3;            // 0..63 (V staging)
  const int vcol = (tid & 7) * 16;

  for (int kt = 0; kt < SEQ / 128; ++kt) {
    const int kb = kt * 128;
    *(uint4*)(&Ks[krow * 72 + kcol])     = *(const uint4*)(&Kh[(size_t)(kb + krow) * DK + kcol]);
    *(uint4*)(&Ks[krow * 72 + kcol + 8]) = *(const uint4*)(&Kh[(size_t)(kb + krow) * DK + kcol + 8]);
    *(uint4*)(&Vs[vrow * 136 + vcol])     = *(const uint4*)(&Vth[(size_t)vrow * SEQ + kb + vcol]);
    *(uint4*)(&Vs[vrow * 136 + vcol + 8]) = *(const uint4*)(&Vth[(size_t)vrow * SEQ + kb + vcol + 8]);
    __syncthreads();

#pragma unroll
    for (int c2 = 0; c2 < 4; ++c2) {        // 32-key chunk
      uint2 pk[2];                          // [kk2]
#pragma unroll
      for (int kk2 = 0; kk2 < 2; ++kk2) {
        const int kk = c2 * 2 + kk2;        // 16-key tile
        bf16x8_t kf0 = *(const bf16x8_t*)(&Ks[(kk * 16 + lrow) * 72 + quad * 8]);
        bf16x8_t kf1 = *(const bf16x8_t*)(&Ks[(kk * 16 + lrow) * 72 + 32 + quad * 8]);
        f32x4_t z = {};
        z = __builtin_amdgcn_mfma_f32_16x16x32_bf16(kf0, qf[0], z, 0, 0, 0);
        z = __builtin_amdgcn_mfma_f32_16x16x32_bf16(kf1, qf[1], z, 0, 0, 0);
        const float p0 = exp2f(z[0]), p1 = exp2f(z[1]);
        const float p2 = exp2f(z[2]), p3 = exp2f(z[3]);
        lsum += (p0 + p1) + (p2 + p3);
        pk[kk2].x = __builtin_amdgcn_perm(__builtin_bit_cast(unsigned, p1),
                                          __builtin_bit_cast(unsigned, p0), 0x07060302u);
        pk[kk2].y = __builtin_amdgcn_perm(__builtin_bit_cast(unsigned, p3),
                                          __builtin_bit_cast(unsigned, p2), 0x07060302u);
      }
      uint4 pfu;
      pfu.x = pk[0].x; pfu.y = pk[0].y; pfu.z = pk[1].x; pfu.w = pk[1].y;
      bf16x8_t pf = __builtin_bit_cast(bf16x8_t, pfu);
#pragma unroll
      for (int nt = 0; nt < 4; ++nt) {
        const bf16_t* vbase = &Vs[(nt * 16 + lrow) * 136 + c2 * 32 + quad * 4];
        bf16x8_t vf;
        *(bf16x4_t*)(&vf)       = *(const bf16x4_t*)(vbase);
        *((bf16x4_t*)(&vf) + 1) = *(const bf16x4_t*)(vbase + 16);
        accO[nt] = __builtin_amdgcn_mfma_f32_16x16x32_bf16(pf, vf, accO[nt], 0, 0, 0);
      }
    }
    __syncthreads();
  }

  // lsum lives at (q = lane&15); reduce over the 4 quads
  lsum += __shfl_xor(lsum, 16);
  lsum += __shfl_xor(lsum, 32);
  // accO rows are q_local = quad*4+r -> pull lsum from lane quad*4+r
  float linv[4];
#pragma unroll
  for (int r = 0; r < 4; r++)
    linv[r] = 1.0f / __shfl(lsum, quad * 4 + r);

  const int b = bh >> 4, h = bh & 15;
#pragma unroll
  for (int nt = 0; nt < 4; nt++)
#pragma unroll
    for (int r = 0; r < 4; r++) {
      const int srowq = q0 + quad * 4 + r;
      const float val = accO[nt][r] * linv[r];
      const size_t o = ((size_t)(b * SEQ + srowq)) * DM + h * DK + nt * 16 + lrow;
      AO[o] = (bf16_t)val;
    }
}

extern "C" void kernel_launch(void* const* d_in, const int* in_sizes, int n_in,
                              void* d_out, int out_size, void* d_ws, size_t ws_size,
                              hipStream_t stream) {
  const float* x  = (const float*)d_in[0];
  const float* wq = (const float*)d_in[1];
  const float* bq = (const float*)d_in[2];
  const float* wk = (const float*)d_in[3];
  const float* bk = (const float*)d_in[4];
  const float* wv = (const float*)d_in[5];
  const float* bv = (const float*)d_in[6];
  const float* wo = (const float*)d_in[7];
  const float* bo = (const float*)d_in[8];
  float* out = (float*)d_out;

  char* ws = (char*)d_ws;
  bf16_t* xb   = (bf16_t*)(ws);             // 8 MB
  bf16_t* wqb  = (bf16_t*)(ws + 8388608);   // 2 MB
  bf16_t* wkb  = (bf16_t*)(ws + 10485760);  // 2 MB
  bf16_t* wvb  = (bf16_t*)(ws + 12582912);  // 2 MB
  bf16_t* wob  = (bf16_t*)(ws + 14680064);  // 2 MB
  bf16_t* Qb   = (bf16_t*)(ws + 16777216);  // 8 MB (B,H,S,dk)
  bf16_t* Kb   = (bf16_t*)(ws + 25165824);  // 8 MB (B,H,S,dk)
  bf16_t* Vtb  = (bf16_t*)(ws + 33554432);  // 8 MB (B,H,dk,S)
  bf16_t* AOb  = (bf16_t*)(ws + 41943040);  // 8 MB (B,S,D)
  float2* lut  = (float2*)(ws + 50331648);  // 512 KB RoPE LUT

  cast_all<<<8192, 256, 0, stream>>>(x, wq, wk, wv, wo, xb);
  rope_lut_kernel<<<256, 256, 0, stream>>>(lut);

  gemm_qk<<<dim3(16, 32), 512, 0, stream>>>(xb, wqb, wkb, bq, bk, lut, Qb, Kb);
  gemm_vt<<<dim3(32, 16), 512, 0, stream>>>(wvb, xb, bv, Vtb);

  attn_kernel<<<dim3(SEQ / 128, 2 * NH), 512, 0, stream>>>(Qb, Kb, Vtb, AOb);

  gemm_out<<<dim3(16, 32), 512, 0, stream>>>(AOb, wob, bo, out);
}

// Round 12
// 226.455 us; speedup vs baseline: 1.1725x; 1.0595x over previous
//
#include <hip/hip_runtime.h>
#include <hip/hip_bf16.h>
#include <math.h>

typedef __bf16 bf16_t;
typedef __bf16 bf16x4_t __attribute__((ext_vector_type(4)));
typedef __bf16 bf16x8_t __attribute__((ext_vector_type(8)));
typedef float  f32x4_t  __attribute__((ext_vector_type(4)));

#define SEQ 2048
#define DM  1024
#define NH  16
#define DK  64
// log2(10000)/32
#define ROPE_C 0.4152410118609203f
// log2(e)/sqrt(dk)
#define EXP_C (1.4426950408889634f / 8.0f)

// async global->LDS, 16B per lane; LDS dst = base + lane*16 (wave-uniform base)
#define GLD16(gp, lp) \
  __builtin_amdgcn_global_load_lds((__attribute__((address_space(1))) const void*)(gp), \
                                   (__attribute__((address_space(3))) void*)(lp), 16, 0, 0)

// ---------------- fused fp32 -> bf16 cast: x, wq, wk, wv, wo ----------------
__global__ __launch_bounds__(256)
void cast_all(const float* __restrict__ x,  const float* __restrict__ wq,
              const float* __restrict__ wk, const float* __restrict__ wv,
              const float* __restrict__ wo, bf16_t* __restrict__ dst) {
  int i = blockIdx.x * 256 + threadIdx.x;   // float4 index, 0..2097151
  const float* s;
  if (i < 1048576) {
    s = x + (size_t)i * 4;
  } else {
    int j = i - 1048576;
    int w = j >> 18;                        // 262144 float4 per weight
    const float* base = (w == 0) ? wq : (w == 1) ? wk : (w == 2) ? wv : wo;
    s = base + (size_t)(j & 262143) * 4;
  }
  float4 v = *(const float4*)s;
  bf16x4_t o;
  o.x = (bf16_t)v.x; o.y = (bf16_t)v.y; o.z = (bf16_t)v.z; o.w = (bf16_t)v.w;
  ((bf16x4_t*)dst)[i] = o;
}

// ---------------- RoPE sin/cos LUT ----------------
__global__ __launch_bounds__(256)
void rope_lut_kernel(float2* __restrict__ lut) {
  int i = blockIdx.x * 256 + threadIdx.x;   // 0..65535
  int s = i >> 5, f = i & 31;
  float ang = (float)s * exp2f(-ROPE_C * (float)f);
  float sn, cs;
  sincosf(ang, &sn, &cs);
  lut[i] = make_float2(sn, cs);
}

// ---------------- Q/K GEMM with fused RoPE (512 thr, global_load_lds) ----------
// Grid (16, 32): bn 0..7 -> Q, bn 8..15 -> K. 128x128 block tile, BK=32,
// wave tile 32x64. LDS UNPADDED (stride 32) — required by global_load_lds's
// lane-ordered destination (m104/m108). Per k-step each wave issues one 1KB
// A-chunk + one 1KB B-chunk (the m93->m97 874-TF staging step).
// NOTE: single epilogue path, no libm (R4-R6 spill). Plain launch_bounds.
__global__ __launch_bounds__(512)
void gemm_qk(const bf16_t* __restrict__ A, const bf16_t* __restrict__ Wq,
             const bf16_t* __restrict__ Wk, const float* __restrict__ bq,
             const float* __restrict__ bk, const float2* __restrict__ lut,
             bf16_t* __restrict__ Qb, bf16_t* __restrict__ Kb) {
  const int K = 1024;
  __shared__ bf16_t As[128 * 32];
  __shared__ bf16_t Bs[128 * 32];

  const int tid  = threadIdx.x;
  const int w    = tid >> 6;                // 0..7
  const int lane = tid & 63;
  const int quad = lane >> 4;
  const int lrow = lane & 15;
  const int wm = (w >> 1) * 32, wn = (w & 1) * 64;
  const int bm = blockIdx.y, bn = blockIdx.x;

  const int isK = bn >> 3;                  // 0 = Q, 1 = K (block-uniform)
  const int bnl = bn & 7;
  const bf16_t* Ablk = A + (size_t)(bm * 128) * K;
  const bf16_t* Bblk = (isK ? Wk : Wq) + (size_t)(bnl * 128) * K;
  const float*  bias = isK ? bk : bq;
  bf16_t* D = isK ? Kb : Qb;

  f32x4_t acc[2][4] = {};

  const int srow = w * 16 + (lane >> 2);    // staging row 0..127
  const int scol = (lane & 3) * 8;          // staging col 0,8,16,24

  for (int k0 = 0; k0 < K; k0 += 32) {
    GLD16(&Ablk[(size_t)srow * K + k0 + scol], &As[w * 512]);
    GLD16(&Bblk[(size_t)srow * K + k0 + scol], &Bs[w * 512]);
    __syncthreads();

    bf16x8_t af[2], bf[4];
#pragma unroll
    for (int mi = 0; mi < 2; mi++)
      af[mi] = *(const bf16x8_t*)(&As[(wm + mi * 16 + lrow) * 32 + quad * 8]);
#pragma unroll
    for (int ni = 0; ni < 4; ni++)
      bf[ni] = *(const bf16x8_t*)(&Bs[(wn + ni * 16 + lrow) * 32 + quad * 8]);
#pragma unroll
    for (int mi = 0; mi < 2; mi++)
#pragma unroll
      for (int ni = 0; ni < 4; ni++)
        acc[mi][ni] = __builtin_amdgcn_mfma_f32_16x16x32_bf16(af[mi], bf[ni], acc[mi][ni], 0, 0, 0);
    __syncthreads();
  }

  const int brow = bm * 128 + wm;
  const int cbase = bnl * 128 + wn;

#pragma unroll
  for (int ni = 0; ni < 4; ni++) {
    const int col = cbase + ni * 16 + lrow;  // 0..1023
    const float bv = bias[col];
    const int t = col & 63;
    const int h = col >> 6;
    const int fidx = t >> 1;
#pragma unroll
    for (int mi = 0; mi < 2; mi++) {
      f32x4_t v = acc[mi][ni];
#pragma unroll
      for (int r = 0; r < 4; r++) {
        const int row = brow + mi * 16 + quad * 4 + r;  // token
        const int s = row & (SEQ - 1);
        float val = v[r] + bv;
        const float2 sc = lut[s * 32 + fidx];
        const float pv = __shfl_xor(val, 1);            // partner column col^1
        val = (t & 1) ? (val * sc.y + pv * sc.x) : (val * sc.y - pv * sc.x);
        const int b = row >> 11;
        const size_t o = (((size_t)(b * NH + h) * SEQ) + s) * DK + t;
        D[o] = (bf16_t)val;
      }
    }
  }
}

// ---------------- V^T GEMM: Vt = (x Wv^T + bv)^T in (B,H,dk,S), 512 thr --------
// 64(f)x128(t) block tile, wave tile 32x32, global_load_lds staging.
__global__ __launch_bounds__(512)
void gemm_vt(const bf16_t* __restrict__ A, const bf16_t* __restrict__ Bx,
             const float* __restrict__ bias, bf16_t* __restrict__ Vtb) {
  const int K = 1024;
  __shared__ bf16_t As[64 * 32];
  __shared__ bf16_t Bs[128 * 32];

  const int tid  = threadIdx.x;
  const int w    = tid >> 6;                // 0..7
  const int lane = tid & 63;
  const int quad = lane >> 4;
  const int lrow = lane & 15;
  const int wm = (w >> 2) * 32, wn = (w & 3) * 32;
  const int bm = blockIdx.y, bn = blockIdx.x;

  const bf16_t* Ablk = A  + (size_t)(bm * 64) * K;    // features
  const bf16_t* Bblk = Bx + (size_t)(bn * 128) * K;   // tokens

  f32x4_t acc[2][2] = {};

  const int srow = (lane >> 2);             // 0..15 within chunk
  const int scol = (lane & 3) * 8;

  for (int k0 = 0; k0 < K; k0 += 32) {
    GLD16(&Bblk[(size_t)(w * 16 + srow) * K + k0 + scol], &Bs[w * 512]);
    if (w < 4)
      GLD16(&Ablk[(size_t)(w * 16 + srow) * K + k0 + scol], &As[w * 512]);
    __syncthreads();

    bf16x8_t af[2], bf[2];
#pragma unroll
    for (int mi = 0; mi < 2; mi++)
      af[mi] = *(const bf16x8_t*)(&As[(wm + mi * 16 + lrow) * 32 + quad * 8]);
#pragma unroll
    for (int ni = 0; ni < 2; ni++)
      bf[ni] = *(const bf16x8_t*)(&Bs[(wn + ni * 16 + lrow) * 32 + quad * 8]);
#pragma unroll
    for (int mi = 0; mi < 2; mi++)
#pragma unroll
      for (int ni = 0; ni < 2; ni++)
        acc[mi][ni] = __builtin_amdgcn_mfma_f32_16x16x32_bf16(af[mi], bf[ni], acc[mi][ni], 0, 0, 0);
    __syncthreads();
  }

  const int fbase = bm * 64 + wm;
  const int tbase = bn * 128 + wn;

#pragma unroll
  for (int ni = 0; ni < 2; ni++) {
    const int t = tbase + ni * 16 + lrow;    // token
    const int b = t >> 11;
    const int s = t & (SEQ - 1);
#pragma unroll
    for (int mi = 0; mi < 2; mi++) {
      f32x4_t v = acc[mi][ni];
      const int f = fbase + mi * 16 + quad * 4;  // feature base (mult of 4)
      const int h = f >> 6, d = f & 63;
#pragma unroll
      for (int r = 0; r < 4; r++)
        Vtb[((size_t)((b * NH + h) * DK + d + r)) * SEQ + s] = (bf16_t)(v[r] + bias[f + r]);
    }
  }
}

// ---------------- output GEMM: out = AO * Wo^T + bo, 512 thr ----------------
// 128(M)x64(N) block tile, wave tile 32x32, global_load_lds staging.
__global__ __launch_bounds__(512)
void gemm_out(const bf16_t* __restrict__ A, const bf16_t* __restrict__ Bw,
              const float* __restrict__ bias, float* __restrict__ D) {
  const int K = 1024;
  __shared__ bf16_t As[128 * 32];
  __shared__ bf16_t Bs[64 * 32];

  const int tid  = threadIdx.x;
  const int w    = tid >> 6;                // 0..7
  const int lane = tid & 63;
  const int quad = lane >> 4;
  const int lrow = lane & 15;
  const int wm = (w >> 1) * 32, wn = (w & 1) * 32;
  const int bm = blockIdx.y, bn = blockIdx.x;

  const bf16_t* Ablk = A  + (size_t)(bm * 128) * K;
  const bf16_t* Bblk = Bw + (size_t)(bn * 64) * K;

  f32x4_t acc[2][2] = {};

  const int srow = (lane >> 2);
  const int scol = (lane & 3) * 8;

  for (int k0 = 0; k0 < K; k0 += 32) {
    GLD16(&Ablk[(size_t)(w * 16 + srow) * K + k0 + scol], &As[w * 512]);
    if (w < 4)
      GLD16(&Bblk[(size_t)(w * 16 + srow) * K + k0 + scol], &Bs[w * 512]);
    __syncthreads();

    bf16x8_t af[2], bf[2];
#pragma unroll
    for (int mi = 0; mi < 2; mi++)
      af[mi] = *(const bf16x8_t*)(&As[(wm + mi * 16 + lrow) * 32 + quad * 8]);
#pragma unroll
    for (int ni = 0; ni < 2; ni++)
      bf[ni] = *(const bf16x8_t*)(&Bs[(wn + ni * 16 + lrow) * 32 + quad * 8]);
#pragma unroll
    for (int mi = 0; mi < 2; mi++)
#pragma unroll
      for (int ni = 0; ni < 2; ni++)
        acc[mi][ni] = __builtin_amdgcn_mfma_f32_16x16x32_bf16(af[mi], bf[ni], acc[mi][ni], 0, 0, 0);
    __syncthreads();
  }

#pragma unroll
  for (int ni = 0; ni < 2; ni++) {
    const int col = bn * 64 + wn + ni * 16 + lrow;
    const float bvv = bias[col];
#pragma unroll
    for (int mi = 0; mi < 2; mi++) {
      f32x4_t v = acc[mi][ni];
#pragma unroll
      for (int r = 0; r < 4; r++) {
        const int row = bm * 128 + wm + mi * 16 + quad * 4 + r;
        D[(size_t)row * DM + col] = v[r] + bvv;
      }
    }
  }
}

// ---------------- flash attention v6 (unchanged from R11) ----------------
__global__ __launch_bounds__(512)
void attn_kernel(const bf16_t* __restrict__ Q, const bf16_t* __restrict__ K,
                 const bf16_t* __restrict__ Vt, bf16_t* __restrict__ AO) {
  __shared__ bf16_t Ks[128 * 72];        // [key][dk]
  __shared__ bf16_t Vs[64 * 136];        // [dk][key]

  const int tid  = threadIdx.x;
  const int w    = tid >> 6;             // 0..7
  const int lane = tid & 63;
  const int quad = lane >> 4;
  const int lrow = lane & 15;
  const int bh = blockIdx.y;
  const int q0 = blockIdx.x * 128 + w * 16;

  const bf16_t* Qh  = Q  + (size_t)bh * SEQ * DK;
  const bf16_t* Kh  = K  + (size_t)bh * SEQ * DK;
  const bf16_t* Vth = Vt + (size_t)bh * DK * SEQ;

  bf16x8_t qf[2];
#pragma unroll
  for (int c = 0; c < 2; c++) {
    bf16x8_t t = *(const bf16x8_t*)(&Qh[(size_t)(q0 + lrow) * DK + c * 32 + quad * 8]);
#pragma unroll
    for (int i = 0; i < 8; i++) t[i] = (bf16_t)((float)t[i] * EXP_C);
    qf[c] = t;
  }

  f32x4_t accO[4] = {};
  float lsum = 0.f;

  const int krow = tid >> 2;            // 0..127 (K staging)
  const int kcol = (tid & 3) * 16;
  const int vrow = tid >> 3;            // 0..63 (V staging)
  const int vcol = (tid & 7) * 16;

  for (int kt = 0; kt < SEQ / 128; ++kt) {
    const int kb = kt * 128;
    *(uint4*)(&Ks[krow * 72 + kcol])     = *(const uint4*)(&Kh[(size_t)(kb + krow) * DK + kcol]);
    *(uint4*)(&Ks[krow * 72 + kcol + 8]) = *(const uint4*)(&Kh[(size_t)(kb + krow) * DK + kcol + 8]);
    *(uint4*)(&Vs[vrow * 136 + vcol])     = *(const uint4*)(&Vth[(size_t)vrow * SEQ + kb + vcol]);
    *(uint4*)(&Vs[vrow * 136 + vcol + 8]) = *(const uint4*)(&Vth[(size_t)vrow * SEQ + kb + vcol + 8]);
    __syncthreads();

#pragma unroll
    for (int c2 = 0; c2 < 4; ++c2) {        // 32-key chunk
      uint2 pk[2];
#pragma unroll
      for (int kk2 = 0; kk2 < 2; ++kk2) {
        const int kk = c2 * 2 + kk2;        // 16-key tile
        bf16x8_t kf0 = *(const bf16x8_t*)(&Ks[(kk * 16 + lrow) * 72 + quad * 8]);
        bf16x8_t kf1 = *(const bf16x8_t*)(&Ks[(kk * 16 + lrow) * 72 + 32 + quad * 8]);
        f32x4_t z = {};
        z = __builtin_amdgcn_mfma_f32_16x16x32_bf16(kf0, qf[0], z, 0, 0, 0);
        z = __builtin_amdgcn_mfma_f32_16x16x32_bf16(kf1, qf[1], z, 0, 0, 0);
        const float p0 = exp2f(z[0]), p1 = exp2f(z[1]);
        const float p2 = exp2f(z[2]), p3 = exp2f(z[3]);
        lsum += (p0 + p1) + (p2 + p3);
        pk[kk2].x = __builtin_amdgcn_perm(__builtin_bit_cast(unsigned, p1),
                                          __builtin_bit_cast(unsigned, p0), 0x07060302u);
        pk[kk2].y = __builtin_amdgcn_perm(__builtin_bit_cast(unsigned, p3),
                                          __builtin_bit_cast(unsigned, p2), 0x07060302u);
      }
      uint4 pfu;
      pfu.x = pk[0].x; pfu.y = pk[0].y; pfu.z = pk[1].x; pfu.w = pk[1].y;
      bf16x8_t pf = __builtin_bit_cast(bf16x8_t, pfu);
#pragma unroll
      for (int nt = 0; nt < 4; ++nt) {
        const bf16_t* vbase = &Vs[(nt * 16 + lrow) * 136 + c2 * 32 + quad * 4];
        bf16x8_t vf;
        *(bf16x4_t*)(&vf)       = *(const bf16x4_t*)(vbase);
        *((bf16x4_t*)(&vf) + 1) = *(const bf16x4_t*)(vbase + 16);
        accO[nt] = __builtin_amdgcn_mfma_f32_16x16x32_bf16(pf, vf, accO[nt], 0, 0, 0);
      }
    }
    __syncthreads();
  }

  lsum += __shfl_xor(lsum, 16);
  lsum += __shfl_xor(lsum, 32);
  float linv[4];
#pragma unroll
  for (int r = 0; r < 4; r++)
    linv[r] = 1.0f / __shfl(lsum, quad * 4 + r);

  const int b = bh >> 4, h = bh & 15;
#pragma unroll
  for (int nt = 0; nt < 4; nt++)
#pragma unroll
    for (int r = 0; r < 4; r++) {
      const int srowq = q0 + quad * 4 + r;
      const float val = accO[nt][r] * linv[r];
      const size_t o = ((size_t)(b * SEQ + srowq)) * DM + h * DK + nt * 16 + lrow;
      AO[o] = (bf16_t)val;
    }
}

extern "C" void kernel_launch(void* const* d_in, const int* in_sizes, int n_in,
                              void* d_out, int out_size, void* d_ws, size_t ws_size,
                              hipStream_t stream) {
  const float* x  = (const float*)d_in[0];
  const float* wq = (const float*)d_in[1];
  const float* bq = (const float*)d_in[2];
  const float* wk = (const float*)d_in[3];
  const float* bk = (const float*)d_in[4];
  const float* wv = (const float*)d_in[5];
  const float* bv = (const float*)d_in[6];
  const float* wo = (const float*)d_in[7];
  const float* bo = (const float*)d_in[8];
  float* out = (float*)d_out;

  char* ws = (char*)d_ws;
  bf16_t* xb   = (bf16_t*)(ws);             // 8 MB
  bf16_t* wqb  = (bf16_t*)(ws + 8388608);   // 2 MB
  bf16_t* wkb  = (bf16_t*)(ws + 10485760);  // 2 MB
  bf16_t* wvb  = (bf16_t*)(ws + 12582912);  // 2 MB
  bf16_t* wob  = (bf16_t*)(ws + 14680064);  // 2 MB
  bf16_t* Qb   = (bf16_t*)(ws + 16777216);  // 8 MB (B,H,S,dk)
  bf16_t* Kb   = (bf16_t*)(ws + 25165824);  // 8 MB (B,H,S,dk)
  bf16_t* Vtb  = (bf16_t*)(ws + 33554432);  // 8 MB (B,H,dk,S)
  bf16_t* AOb  = (bf16_t*)(ws + 41943040);  // 8 MB (B,S,D)
  float2* lut  = (float2*)(ws + 50331648);  // 512 KB RoPE LUT

  cast_all<<<8192, 256, 0, stream>>>(x, wq, wk, wv, wo, xb);
  rope_lut_kernel<<<256, 256, 0, stream>>>(lut);

  gemm_qk<<<dim3(16, 32), 512, 0, stream>>>(xb, wqb, wkb, bq, bk, lut, Qb, Kb);
  gemm_vt<<<dim3(32, 16), 512, 0, stream>>>(wvb, xb, bv, Vtb);

  attn_kernel<<<dim3(SEQ / 128, 2 * NH), 512, 0, stream>>>(Qb, Kb, Vtb, AOb);

  gemm_out<<<dim3(16, 32), 512, 0, stream>>>(AOb, wob, bo, out);
}

// Round 13
// 223.660 us; speedup vs baseline: 1.1872x; 1.0125x over previous
//
#include <hip/hip_runtime.h>
#include <hip/hip_bf16.h>
#include <math.h>

typedef __bf16 bf16_t;
typedef __bf16 bf16x4_t __attribute__((ext_vector_type(4)));
typedef __bf16 bf16x8_t __attribute__((ext_vector_type(8)));
typedef float  f32x4_t  __attribute__((ext_vector_type(4)));

#define SEQ 2048
#define DM  1024
#define NH  16
#define DK  64
// log2(10000)/32
#define ROPE_C 0.4152410118609203f
// log2(e)/sqrt(dk)
#define EXP_C (1.4426950408889634f / 8.0f)

// async global->LDS, 16B per lane; LDS dst = base + lane*16 (wave-uniform base)
#define GLD16(gp, lp) \
  __builtin_amdgcn_global_load_lds((__attribute__((address_space(1))) const void*)(gp), \
                                   (__attribute__((address_space(3))) void*)(lp), 16, 0, 0)

// ---------------- fused fp32 -> bf16 cast: x, wq, wk, wv, wo ----------------
__global__ __launch_bounds__(256)
void cast_all(const float* __restrict__ x,  const float* __restrict__ wq,
              const float* __restrict__ wk, const float* __restrict__ wv,
              const float* __restrict__ wo, bf16_t* __restrict__ dst) {
  int i = blockIdx.x * 256 + threadIdx.x;   // float4 index, 0..2097151
  const float* s;
  if (i < 1048576) {
    s = x + (size_t)i * 4;
  } else {
    int j = i - 1048576;
    int w = j >> 18;                        // 262144 float4 per weight
    const float* base = (w == 0) ? wq : (w == 1) ? wk : (w == 2) ? wv : wo;
    s = base + (size_t)(j & 262143) * 4;
  }
  float4 v = *(const float4*)s;
  bf16x4_t o;
  o.x = (bf16_t)v.x; o.y = (bf16_t)v.y; o.z = (bf16_t)v.z; o.w = (bf16_t)v.w;
  ((bf16x4_t*)dst)[i] = o;
}

// ---------------- RoPE sin/cos LUT ----------------
__global__ __launch_bounds__(256)
void rope_lut_kernel(float2* __restrict__ lut) {
  int i = blockIdx.x * 256 + threadIdx.x;   // 0..65535
  int s = i >> 5, f = i & 31;
  float ang = (float)s * exp2f(-ROPE_C * (float)f);
  float sn, cs;
  sincosf(ang, &sn, &cs);
  lut[i] = make_float2(sn, cs);
}

// ---------------- Q/K GEMM, m97 structure: 256 thr, 64x64 wave tile ------------
// Grid (16, 32): bn 0..7 -> Q, bn 8..15 -> K. 128x128 tile, BK=32, acc[4][4]
// (16 MFMA : 8 ds_read_b128 : 4 GLD16 per K-step — the 874-TF density).
// LDS unpadded stride 32 (GLD16 lane-ordered dst; b128 reads bank-balanced).
// NOTE: single epilogue path, no libm (R4-R6 spill). Plain launch_bounds.
__global__ __launch_bounds__(256)
void gemm_qk(const bf16_t* __restrict__ A, const bf16_t* __restrict__ Wq,
             const bf16_t* __restrict__ Wk, const float* __restrict__ bq,
             const float* __restrict__ bk, const float2* __restrict__ lut,
             bf16_t* __restrict__ Qb, bf16_t* __restrict__ Kb) {
  const int K = 1024;
  __shared__ bf16_t As[128 * 32];
  __shared__ bf16_t Bs[128 * 32];

  const int tid  = threadIdx.x;
  const int w    = tid >> 6;                // 0..3
  const int lane = tid & 63;
  const int quad = lane >> 4;
  const int lrow = lane & 15;
  const int wm = (w >> 1) * 64, wn = (w & 1) * 64;
  const int bm = blockIdx.y, bn = blockIdx.x;

  const int isK = bn >> 3;                  // 0 = Q, 1 = K (block-uniform)
  const int bnl = bn & 7;
  const bf16_t* Ablk = A + (size_t)(bm * 128) * K;
  const bf16_t* Bblk = (isK ? Wk : Wq) + (size_t)(bnl * 128) * K;
  const float*  bias = isK ? bk : bq;
  bf16_t* D = isK ? Kb : Qb;

  f32x4_t acc[4][4] = {};

  const int srow = lane >> 2;               // 0..15 within 16-row chunk
  const int scol = (lane & 3) * 8;          // 0,8,16,24

  for (int k0 = 0; k0 < K; k0 += 32) {
    GLD16(&Ablk[(size_t)(w * 32 + srow) * K + k0 + scol],      &As[(w * 32) * 32]);
    GLD16(&Ablk[(size_t)(w * 32 + 16 + srow) * K + k0 + scol], &As[(w * 32 + 16) * 32]);
    GLD16(&Bblk[(size_t)(w * 32 + srow) * K + k0 + scol],      &Bs[(w * 32) * 32]);
    GLD16(&Bblk[(size_t)(w * 32 + 16 + srow) * K + k0 + scol], &Bs[(w * 32 + 16) * 32]);
    __syncthreads();

    bf16x8_t af[4], bf[4];
#pragma unroll
    for (int mi = 0; mi < 4; mi++)
      af[mi] = *(const bf16x8_t*)(&As[(wm + mi * 16 + lrow) * 32 + quad * 8]);
#pragma unroll
    for (int ni = 0; ni < 4; ni++)
      bf[ni] = *(const bf16x8_t*)(&Bs[(wn + ni * 16 + lrow) * 32 + quad * 8]);
#pragma unroll
    for (int mi = 0; mi < 4; mi++)
#pragma unroll
      for (int ni = 0; ni < 4; ni++)
        acc[mi][ni] = __builtin_amdgcn_mfma_f32_16x16x32_bf16(af[mi], bf[ni], acc[mi][ni], 0, 0, 0);
    __syncthreads();
  }

  const int brow = bm * 128 + wm;
  const int cbase = bnl * 128 + wn;

#pragma unroll
  for (int ni = 0; ni < 4; ni++) {
    const int col = cbase + ni * 16 + lrow;  // 0..1023
    const float bv = bias[col];
    const int t = col & 63;
    const int h = col >> 6;
    const int fidx = t >> 1;
#pragma unroll
    for (int mi = 0; mi < 4; mi++) {
      f32x4_t v = acc[mi][ni];
#pragma unroll
      for (int r = 0; r < 4; r++) {
        const int row = brow + mi * 16 + quad * 4 + r;  // token
        const int s = row & (SEQ - 1);
        float val = v[r] + bv;
        const float2 sc = lut[s * 32 + fidx];
        const float pv = __shfl_xor(val, 1);            // partner column col^1
        val = (t & 1) ? (val * sc.y + pv * sc.x) : (val * sc.y - pv * sc.x);
        const int b = row >> 11;
        const size_t o = (((size_t)(b * NH + h) * SEQ) + s) * DK + t;
        D[o] = (bf16_t)val;
      }
    }
  }
}

// ---------------- V^T GEMM: Vt = (x Wv^T + bv)^T, 256 thr -------------------
// 64(f)x128(t) tile, wave tile 32(f)x64(t): acc[2][4] = 8 MFMA : 6 reads : 3 GLD.
// Grid (32, 16) = 512 blocks.
__global__ __launch_bounds__(256)
void gemm_vt(const bf16_t* __restrict__ A, const bf16_t* __restrict__ Bx,
             const float* __restrict__ bias, bf16_t* __restrict__ Vtb) {
  const int K = 1024;
  __shared__ bf16_t As[64 * 32];
  __shared__ bf16_t Bs[128 * 32];

  const int tid  = threadIdx.x;
  const int w    = tid >> 6;                // 0..3
  const int lane = tid & 63;
  const int quad = lane >> 4;
  const int lrow = lane & 15;
  const int wm = (w >> 1) * 32, wn = (w & 1) * 64;
  const int bm = blockIdx.y, bn = blockIdx.x;

  const bf16_t* Ablk = A  + (size_t)(bm * 64) * K;    // features
  const bf16_t* Bblk = Bx + (size_t)(bn * 128) * K;   // tokens

  f32x4_t acc[2][4] = {};

  const int srow = lane >> 2;
  const int scol = (lane & 3) * 8;

  for (int k0 = 0; k0 < K; k0 += 32) {
    GLD16(&Ablk[(size_t)(w * 16 + srow) * K + k0 + scol],      &As[(w * 16) * 32]);
    GLD16(&Bblk[(size_t)(w * 32 + srow) * K + k0 + scol],      &Bs[(w * 32) * 32]);
    GLD16(&Bblk[(size_t)(w * 32 + 16 + srow) * K + k0 + scol], &Bs[(w * 32 + 16) * 32]);
    __syncthreads();

    bf16x8_t af[2], bf[4];
#pragma unroll
    for (int mi = 0; mi < 2; mi++)
      af[mi] = *(const bf16x8_t*)(&As[(wm + mi * 16 + lrow) * 32 + quad * 8]);
#pragma unroll
    for (int ni = 0; ni < 4; ni++)
      bf[ni] = *(const bf16x8_t*)(&Bs[(wn + ni * 16 + lrow) * 32 + quad * 8]);
#pragma unroll
    for (int mi = 0; mi < 2; mi++)
#pragma unroll
      for (int ni = 0; ni < 4; ni++)
        acc[mi][ni] = __builtin_amdgcn_mfma_f32_16x16x32_bf16(af[mi], bf[ni], acc[mi][ni], 0, 0, 0);
    __syncthreads();
  }

  const int fbase = bm * 64 + wm;
  const int tbase = bn * 128 + wn;

#pragma unroll
  for (int ni = 0; ni < 4; ni++) {
    const int t = tbase + ni * 16 + lrow;    // token
    const int b = t >> 11;
    const int s = t & (SEQ - 1);
#pragma unroll
    for (int mi = 0; mi < 2; mi++) {
      f32x4_t v = acc[mi][ni];
      const int f = fbase + mi * 16 + quad * 4;  // feature base (mult of 4)
      const int h = f >> 6, d = f & 63;
#pragma unroll
      for (int r = 0; r < 4; r++)
        Vtb[((size_t)((b * NH + h) * DK + d + r)) * SEQ + s] = (bf16_t)(v[r] + bias[f + r]);
    }
  }
}

// ---------------- output GEMM: out = AO * Wo^T + bo, 256 thr ----------------
// 128(M)x64(N) tile, wave tile 64x32: acc[4][2] = 8 MFMA : 6 reads : 3 GLD.
// Grid (16, 32) = 512 blocks.
__global__ __launch_bounds__(256)
void gemm_out(const bf16_t* __restrict__ A, const bf16_t* __restrict__ Bw,
              const float* __restrict__ bias, float* __restrict__ D) {
  const int K = 1024;
  __shared__ bf16_t As[128 * 32];
  __shared__ bf16_t Bs[64 * 32];

  const int tid  = threadIdx.x;
  const int w    = tid >> 6;                // 0..3
  const int lane = tid & 63;
  const int quad = lane >> 4;
  const int lrow = lane & 15;
  const int wm = (w >> 1) * 64, wn = (w & 1) * 32;
  const int bm = blockIdx.y, bn = blockIdx.x;

  const bf16_t* Ablk = A  + (size_t)(bm * 128) * K;
  const bf16_t* Bblk = Bw + (size_t)(bn * 64) * K;

  f32x4_t acc[4][2] = {};

  const int srow = lane >> 2;
  const int scol = (lane & 3) * 8;

  for (int k0 = 0; k0 < K; k0 += 32) {
    GLD16(&Ablk[(size_t)(w * 32 + srow) * K + k0 + scol],      &As[(w * 32) * 32]);
    GLD16(&Ablk[(size_t)(w * 32 + 16 + srow) * K + k0 + scol], &As[(w * 32 + 16) * 32]);
    GLD16(&Bblk[(size_t)(w * 16 + srow) * K + k0 + scol],      &Bs[(w * 16) * 32]);
    __syncthreads();

    bf16x8_t af[4], bf[2];
#pragma unroll
    for (int mi = 0; mi < 4; mi++)
      af[mi] = *(const bf16x8_t*)(&As[(wm + mi * 16 + lrow) * 32 + quad * 8]);
#pragma unroll
    for (int ni = 0; ni < 2; ni++)
      bf[ni] = *(const bf16x8_t*)(&Bs[(wn + ni * 16 + lrow) * 32 + quad * 8]);
#pragma unroll
    for (int mi = 0; mi < 4; mi++)
#pragma unroll
      for (int ni = 0; ni < 2; ni++)
        acc[mi][ni] = __builtin_amdgcn_mfma_f32_16x16x32_bf16(af[mi], bf[ni], acc[mi][ni], 0, 0, 0);
    __syncthreads();
  }

#pragma unroll
  for (int ni = 0; ni < 2; ni++) {
    const int col = bn * 64 + wn + ni * 16 + lrow;
    const float bvv = bias[col];
#pragma unroll
    for (int mi = 0; mi < 4; mi++) {
      f32x4_t v = acc[mi][ni];
#pragma unroll
      for (int r = 0; r < 4; r++) {
        const int row = bm * 128 + wm + mi * 16 + quad * 4 + r;
        D[(size_t)row * DM + col] = v[r] + bvv;
      }
    }
  }
}

// ---------------- flash attention v6 (unchanged from R11/R12) ----------------
__global__ __launch_bounds__(512)
void attn_kernel(const bf16_t* __restrict__ Q, const bf16_t* __restrict__ K,
                 const bf16_t* __restrict__ Vt, bf16_t* __restrict__ AO) {
  __shared__ bf16_t Ks[128 * 72];        // [key][dk]
  __shared__ bf16_t Vs[64 * 136];        // [dk][key]

  const int tid  = threadIdx.x;
  const int w    = tid >> 6;             // 0..7
  const int lane = tid & 63;
  const int quad = lane >> 4;
  const int lrow = lane & 15;
  const int bh = blockIdx.y;
  const int q0 = blockIdx.x * 128 + w * 16;

  const bf16_t* Qh  = Q  + (size_t)bh * SEQ * DK;
  const bf16_t* Kh  = K  + (size_t)bh * SEQ * DK;
  const bf16_t* Vth = Vt + (size_t)bh * DK * SEQ;

  bf16x8_t qf[2];
#pragma unroll
  for (int c = 0; c < 2; c++) {
    bf16x8_t t = *(const bf16x8_t*)(&Qh[(size_t)(q0 + lrow) * DK + c * 32 + quad * 8]);
#pragma unroll
    for (int i = 0; i < 8; i++) t[i] = (bf16_t)((float)t[i] * EXP_C);
    qf[c] = t;
  }

  f32x4_t accO[4] = {};
  float lsum = 0.f;

  const int krow = tid >> 2;            // 0..127 (K staging)
  const int kcol = (tid & 3) * 16;
  const int vrow = tid >> 3;            // 0..63 (V staging)
  const int vcol = (tid & 7) * 16;

  for (int kt = 0; kt < SEQ / 128; ++kt) {
    const int kb = kt * 128;
    *(uint4*)(&Ks[krow * 72 + kcol])     = *(const uint4*)(&Kh[(size_t)(kb + krow) * DK + kcol]);
    *(uint4*)(&Ks[krow * 72 + kcol + 8]) = *(const uint4*)(&Kh[(size_t)(kb + krow) * DK + kcol + 8]);
    *(uint4*)(&Vs[vrow * 136 + vcol])     = *(const uint4*)(&Vth[(size_t)vrow * SEQ + kb + vcol]);
    *(uint4*)(&Vs[vrow * 136 + vcol + 8]) = *(const uint4*)(&Vth[(size_t)vrow * SEQ + kb + vcol + 8]);
    __syncthreads();

#pragma unroll
    for (int c2 = 0; c2 < 4; ++c2) {        // 32-key chunk
      uint2 pk[2];
#pragma unroll
      for (int kk2 = 0; kk2 < 2; ++kk2) {
        const int kk = c2 * 2 + kk2;        // 16-key tile
        bf16x8_t kf0 = *(const bf16x8_t*)(&Ks[(kk * 16 + lrow) * 72 + quad * 8]);
        bf16x8_t kf1 = *(const bf16x8_t*)(&Ks[(kk * 16 + lrow) * 72 + 32 + quad * 8]);
        f32x4_t z = {};
        z = __builtin_amdgcn_mfma_f32_16x16x32_bf16(kf0, qf[0], z, 0, 0, 0);
        z = __builtin_amdgcn_mfma_f32_16x16x32_bf16(kf1, qf[1], z, 0, 0, 0);
        const float p0 = exp2f(z[0]), p1 = exp2f(z[1]);
        const float p2 = exp2f(z[2]), p3 = exp2f(z[3]);
        lsum += (p0 + p1) + (p2 + p3);
        pk[kk2].x = __builtin_amdgcn_perm(__builtin_bit_cast(unsigned, p1),
                                          __builtin_bit_cast(unsigned, p0), 0x07060302u);
        pk[kk2].y = __builtin_amdgcn_perm(__builtin_bit_cast(unsigned, p3),
                                          __builtin_bit_cast(unsigned, p2), 0x07060302u);
      }
      uint4 pfu;
      pfu.x = pk[0].x; pfu.y = pk[0].y; pfu.z = pk[1].x; pfu.w = pk[1].y;
      bf16x8_t pf = __builtin_bit_cast(bf16x8_t, pfu);
#pragma unroll
      for (int nt = 0; nt < 4; ++nt) {
        const bf16_t* vbase = &Vs[(nt * 16 + lrow) * 136 + c2 * 32 + quad * 4];
        bf16x8_t vf;
        *(bf16x4_t*)(&vf)       = *(const bf16x4_t*)(vbase);
        *((bf16x4_t*)(&vf) + 1) = *(const bf16x4_t*)(vbase + 16);
        accO[nt] = __builtin_amdgcn_mfma_f32_16x16x32_bf16(pf, vf, accO[nt], 0, 0, 0);
      }
    }
    __syncthreads();
  }

  lsum += __shfl_xor(lsum, 16);
  lsum += __shfl_xor(lsum, 32);
  float linv[4];
#pragma unroll
  for (int r = 0; r < 4; r++)
    linv[r] = 1.0f / __shfl(lsum, quad * 4 + r);

  const int b = bh >> 4, h = bh & 15;
#pragma unroll
  for (int nt = 0; nt < 4; nt++)
#pragma unroll
    for (int r = 0; r < 4; r++) {
      const int srowq = q0 + quad * 4 + r;
      const float val = accO[nt][r] * linv[r];
      const size_t o = ((size_t)(b * SEQ + srowq)) * DM + h * DK + nt * 16 + lrow;
      AO[o] = (bf16_t)val;
    }
}

extern "C" void kernel_launch(void* const* d_in, const int* in_sizes, int n_in,
                              void* d_out, int out_size, void* d_ws, size_t ws_size,
                              hipStream_t stream) {
  const float* x  = (const float*)d_in[0];
  const float* wq = (const float*)d_in[1];
  const float* bq = (const float*)d_in[2];
  const float* wk = (const float*)d_in[3];
  const float* bk = (const float*)d_in[4];
  const float* wv = (const float*)d_in[5];
  const float* bv = (const float*)d_in[6];
  const float* wo = (const float*)d_in[7];
  const float* bo = (const float*)d_in[8];
  float* out = (float*)d_out;

  char* ws = (char*)d_ws;
  bf16_t* xb   = (bf16_t*)(ws);             // 8 MB
  bf16_t* wqb  = (bf16_t*)(ws + 8388608);   // 2 MB
  bf16_t* wkb  = (bf16_t*)(ws + 10485760);  // 2 MB
  bf16_t* wvb  = (bf16_t*)(ws + 12582912);  // 2 MB
  bf16_t* wob  = (bf16_t*)(ws + 14680064);  // 2 MB
  bf16_t* Qb   = (bf16_t*)(ws + 16777216);  // 8 MB (B,H,S,dk)
  bf16_t* Kb   = (bf16_t*)(ws + 25165824);  // 8 MB (B,H,S,dk)
  bf16_t* Vtb  = (bf16_t*)(ws + 33554432);  // 8 MB (B,H,dk,S)
  bf16_t* AOb  = (bf16_t*)(ws + 41943040);  // 8 MB (B,S,D)
  float2* lut  = (float2*)(ws + 50331648);  // 512 KB RoPE LUT

  cast_all<<<8192, 256, 0, stream>>>(x, wq, wk, wv, wo, xb);
  rope_lut_kernel<<<256, 256, 0, stream>>>(lut);

  gemm_qk<<<dim3(16, 32), 256, 0, stream>>>(xb, wqb, wkb, bq, bk, lut, Qb, Kb);
  gemm_vt<<<dim3(32, 16), 256, 0, stream>>>(wvb, xb, bv, Vtb);

  attn_kernel<<<dim3(SEQ / 128, 2 * NH), 512, 0, stream>>>(Qb, Kb, Vtb, AOb);

  gemm_out<<<dim3(16, 32), 256, 0, stream>>>(AOb, wob, bo, out);
}